// Round 1
// baseline (335.180 us; speedup 1.0000x reference)
//
#include <hip/hip_runtime.h>
#include <math.h>

// SpectralConv3d via DHT identities.
// Key math (verified against delta-input toys):
//   r = Re(F) - Im(G), F = fftn(x), G = fftn(flip(x,-1)) = e^{2pi i k3/N} F[k1,k2,-k3]
//   ||r||^2 = (N^3/2) * (2*sum(x^2) + c1 - c2)       [cross term provably 0]
//     c1 = sum x[n] * x[(-n1)%N,(-n2)%N,(-n3)%N]
//     c2 = sum x[n] * x[(-n1)%N,(-n2)%N,(-(n3+2))%N]
//   corner r: stage1 contract n3 (k3 in 0..7, conj covers -k3) -> P complex
//             stage2/3 contract n2,n1 over real fields Pr,Pi -> U,V complex
//             r = Ur - Vi - sin(t)*(Ur+Vi) - cos(t)*(Ui-Vr),  t = 2pi k3/64
//   mixing: conv = 0.5 * sum_i [ (x+xn)*w + (x-xn)*wn ],  neg mod 8
//   second norm: ||Y||^2 = (N^3/2)*(2*sum(conv^2) + conv[0,0,0]^2)
//   expansion: Y[k] = sum_{n3} ReB*C1[k3,n3] + ImB*C2[k3,n3]
//     C1 = cos(w) - sin(w+t), C2 = sin(w) - cos(w+t), w = 2pi k3 n3/64

constexpr int NT = 262144;  // 64^3
constexpr float TWOPI_64 = 0.09817477042468103f;  // 2*pi/64

// ws float offsets
//   P    : [128][8][64][64][2]  = 8388608   (aliased by A2 later)
//   red1 : [128][3]             at 8388608
//   xh   : [128][512]           at 8388992
//   conv : [128][512]           at 8454528
//   inv2 : [128]                at 8520064
//   A1   : [128][8192]          at 8520192   (total 9568768 floats ~ 38.3 MB)

// ---------------- K1: stage1 (n3 contraction) + norm reductions ----------------
__global__ __launch_bounds__(256) void k_fwd1(const float* __restrict__ x,
                                              float* __restrict__ P,
                                              float* __restrict__ red1) {
  __shared__ float As[64 * 65];
  __shared__ float Bs[64 * 65];
  __shared__ float c64[64], s64[64];
  __shared__ float rsm[12];
  const int t = threadIdx.x;
  const int j = blockIdx.x;       // 0..32
  const int bc = blockIdx.y;      // 0..127
  const int n1a = j, n1b = (64 - j) & 63;
  const bool paired = (n1a != n1b);
  if (t < 64) { float ang = TWOPI_64 * t; c64[t] = cosf(ang); s64[t] = sinf(ang); }
  const float* xa = x + ((size_t)bc << 18) + (n1a << 12);
  const float* xb = x + ((size_t)bc << 18) + (n1b << 12);
  for (int q = 0; q < 16; ++q) {
    int l = t + (q << 8);
    int r = l >> 6, c = l & 63;
    As[r * 65 + c] = xa[l];
    Bs[r * 65 + c] = xb[l];   // == xa when unpaired (harmless)
  }
  __syncthreads();
  {
    const int n2 = t & 63;
    const int k3a = t >> 6;       // 0..3
    const int k3b = k3a + 4;
    float ca = 1.f, sa = 0.f, cb = 1.f, sb = 0.f;
    const float dca = c64[k3a], dsa = s64[k3a];
    const float dcb = c64[k3b], dsb = s64[k3b];
    float reA0 = 0, imA0 = 0, reA1 = 0, imA1 = 0;
    float reB0 = 0, imB0 = 0, reB1 = 0, imB1 = 0;
    const float* Ar = &As[n2 * 65];
    const float* Br = &Bs[n2 * 65];
    for (int n3 = 0; n3 < 64; ++n3) {
      float va = Ar[n3], vb = Br[n3];
      reA0 += va * ca; imA0 -= va * sa;
      reB0 += vb * ca; imB0 -= vb * sa;
      reA1 += va * cb; imA1 -= va * sb;
      reB1 += vb * cb; imB1 -= vb * sb;
      float nca = ca * dca - sa * dsa; sa = sa * dca + ca * dsa; ca = nca;
      float ncb = cb * dcb - sb * dsb; sb = sb * dcb + cb * dsb; cb = ncb;
    }
    float2* Pp = (float2*)P;
    Pp[(((size_t)bc * 8 + k3a) * 64 + n1a) * 64 + n2] = make_float2(reA0, imA0);
    Pp[(((size_t)bc * 8 + k3b) * 64 + n1a) * 64 + n2] = make_float2(reA1, imA1);
    if (paired) {
      Pp[(((size_t)bc * 8 + k3a) * 64 + n1b) * 64 + n2] = make_float2(reB0, imB0);
      Pp[(((size_t)bc * 8 + k3b) * 64 + n1b) * 64 + n2] = make_float2(reB1, imB1);
    }
  }
  // reductions: ss, c1, c2
  float ssp = 0.f, c1p = 0.f, c2p = 0.f;
  for (int q = 0; q < 16; ++q) {
    int l = t + (q << 8);
    int r = l >> 6, c = l & 63;
    float a = As[r * 65 + c];
    int m2 = (64 - r) & 63;
    int m3 = (64 - c) & 63;
    int m3b = (62 - c) & 63;
    float b1 = Bs[m2 * 65 + m3];
    float b2 = Bs[m2 * 65 + m3b];
    ssp += a * a;
    if (paired) { float bb = Bs[r * 65 + c]; ssp += bb * bb; }
    c1p += a * b1;
    c2p += a * b2;
  }
  if (paired) { c1p *= 2.f; c2p *= 2.f; }
  for (int off = 32; off; off >>= 1) {
    ssp += __shfl_down(ssp, off);
    c1p += __shfl_down(c1p, off);
    c2p += __shfl_down(c2p, off);
  }
  const int lane = t & 63, wid = t >> 6;
  if (lane == 0) { rsm[wid * 3] = ssp; rsm[wid * 3 + 1] = c1p; rsm[wid * 3 + 2] = c2p; }
  __syncthreads();
  if (t == 0) {
    atomicAdd(&red1[bc * 3 + 0], rsm[0] + rsm[3] + rsm[6] + rsm[9]);
    atomicAdd(&red1[bc * 3 + 1], rsm[1] + rsm[4] + rsm[7] + rsm[10]);
    atomicAdd(&red1[bc * 3 + 2], rsm[2] + rsm[5] + rsm[8] + rsm[11]);
  }
}

// ---------------- K2: stage2/3 (n2,n1 contraction) + corner r + normalize ----------------
__global__ __launch_bounds__(256) void k_fwd2(const float* __restrict__ P,
                                              const float* __restrict__ red1,
                                              float* __restrict__ xh) {
  __shared__ float Pf[64 * 130];
  __shared__ float S2L[2048];
  __shared__ float U3L[256];
  __shared__ float c64[64], s64[64];
  const int t = threadIdx.x;
  const int k3 = blockIdx.x;   // 0..7
  const int bc = blockIdx.y;
  if (t < 64) { float ang = TWOPI_64 * t; c64[t] = cosf(ang); s64[t] = sinf(ang); }
  const float4* Pb4 = (const float4*)(P + ((size_t)(bc * 8 + k3) << 13));
  for (int q = 0; q < 8; ++q) {
    int l4 = t + (q << 8);
    float4 v = Pb4[l4];
    int fl = l4 << 2;
    int row = fl >> 7, col = fl & 127;
    float2* d = (float2*)&Pf[row * 130 + col];
    d[0] = make_float2(v.x, v.y);
    d[1] = make_float2(v.z, v.w);
  }
  __syncthreads();
  {  // stage2: contract n2 for k2 in 0..7 over both real fields
    const int n1 = t >> 2;
    const int f = (t >> 1) & 1;
    const int kh = t & 1;
    float are[4] = {0, 0, 0, 0}, aim[4] = {0, 0, 0, 0};
    float rc[4], rs_[4], dc[4], ds_[4];
#pragma unroll
    for (int q = 0; q < 4; ++q) {
      int k2 = 2 * q + kh;
      rc[q] = 1.f; rs_[q] = 0.f;
      dc[q] = c64[k2]; ds_[q] = s64[k2];
    }
    const float* col0 = &Pf[n1 * 130 + f];
    for (int n2 = 0; n2 < 64; ++n2) {
      float v = col0[2 * n2];
#pragma unroll
      for (int q = 0; q < 4; ++q) {
        are[q] += v * rc[q]; aim[q] -= v * rs_[q];
        float nc = rc[q] * dc[q] - rs_[q] * ds_[q];
        rs_[q] = rs_[q] * dc[q] + rc[q] * ds_[q];
        rc[q] = nc;
      }
    }
    float2* S2 = (float2*)S2L;
#pragma unroll
    for (int q = 0; q < 4; ++q) {
      int k2 = 2 * q + kh;
      S2[(n1 * 2 + f) * 8 + k2] = make_float2(are[q], aim[q]);
    }
  }
  __syncthreads();
  if (t < 128) {  // stage3: contract n1 for k1 in 0..7 (complex)
    const int f = t >> 6, k1 = (t >> 3) & 7, k2 = t & 7;
    float rc = 1.f, rs2 = 0.f;
    const float dc = c64[k1], ds2 = s64[k1];
    float re = 0.f, im = 0.f;
    const float2* S2 = (const float2*)S2L;
    for (int n1 = 0; n1 < 64; ++n1) {
      float2 ab = S2[(n1 * 2 + f) * 8 + k2];
      re += ab.x * rc + ab.y * rs2;
      im += ab.y * rc - ab.x * rs2;
      float nc = rc * dc - rs2 * ds2;
      rs2 = rs2 * dc + rc * ds2;
      rc = nc;
    }
    ((float2*)U3L)[(f * 8 + k1) * 8 + k2] = make_float2(re, im);
  }
  __syncthreads();
  if (t < 64) {
    float ssv = red1[bc * 3], c1v = red1[bc * 3 + 1], c2v = red1[bc * 3 + 2];
    float nsq = 0.5f * (float)NT * (2.f * ssv + c1v - c2v);
    float inv1 = nsq > 0.f ? rsqrtf(nsq) : 0.f;
    const int k1 = t >> 3, k2 = t & 7;
    const float2* U3 = (const float2*)U3L;
    float2 U = U3[k1 * 8 + k2];
    float2 V = U3[64 + k1 * 8 + k2];
    float ct = c64[k3], st = s64[k3];
    float r = U.x - V.y - st * (U.x + V.y) - ct * (U.y - V.x);
    xh[bc * 512 + (k1 * 8 + k2) * 8 + k3] = r * inv1;
  }
}

// ---------------- K3: channel mixing ----------------
__global__ __launch_bounds__(256) void k_mix(const float* __restrict__ xh,
                                             const float* __restrict__ w,
                                             float* __restrict__ convG) {
  __shared__ float xsh[16384];
  const int t = threadIdx.x;
  const int bc2 = blockIdx.x;
  const int b = bc2 >> 5, o = bc2 & 31;
  const float4* xb4 = (const float4*)(xh + ((size_t)b << 14));
  float4* xs4 = (float4*)xsh;
  for (int q = 0; q < 16; ++q) xs4[t + (q << 8)] = xb4[t + (q << 8)];
  __syncthreads();
  for (int q = 0; q < 2; ++q) {
    int k = t + (q << 8);
    int k1 = k >> 6, k2 = (k >> 3) & 7, k3 = k & 7;
    int nk = (((8 - k1) & 7) << 6) + (((8 - k2) & 7) << 3) + ((8 - k3) & 7);
    float acc = 0.f;
    for (int i = 0; i < 32; ++i) {
      float xa = xsh[(i << 9) + k];
      float xn = xsh[(i << 9) + nk];
      const float* wr = w + (((size_t)i * 32 + o) << 9);
      acc += (xa + xn) * wr[k] + (xa - xn) * wr[nk];
    }
    convG[((size_t)bc2 << 9) + k] = 0.5f * acc;
  }
}

// ---------------- K4a: expansion stage A (n1 -> all k1) + second norm ----------------
__global__ __launch_bounds__(256) void k_expA(const float* __restrict__ convG,
                                              float* __restrict__ A1,
                                              float* __restrict__ inv2) {
  __shared__ float c64[64], s64[64];
  const int t = threadIdx.x;
  const int bc2 = blockIdx.x;
  if (t < 64) { float ang = TWOPI_64 * t; c64[t] = cosf(ang); s64[t] = sinf(ang); }
  const int col = t & 63;        // n2*8+n3
  const int quarter = t >> 6;
  const float* cb = convG + ((size_t)bc2 << 9);
  float cv[8];
#pragma unroll
  for (int n1 = 0; n1 < 8; ++n1) cv[n1] = cb[(n1 << 6) + col];
  if (quarter == 0) {
    float p = 0.f;
#pragma unroll
    for (int n1 = 0; n1 < 8; ++n1) p += cv[n1] * cv[n1];
    for (int off = 32; off; off >>= 1) p += __shfl_down(p, off);
    if (t == 0) {
      float c000 = cv[0];
      float nsq = 0.5f * (float)NT * (2.f * p + c000 * c000);
      float nrm = sqrtf(nsq);
      inv2[bc2] = nrm > 0.f ? 1.f / (nrm * (float)NT) : 0.f;
    }
  }
  __syncthreads();
  float2* A1p = (float2*)(A1 + ((size_t)bc2 << 13));
  for (int it = 0; it < 16; ++it) {
    int k1 = quarter + (it << 2);
    float re = 0.f, im = 0.f;
#pragma unroll
    for (int n1 = 0; n1 < 8; ++n1) {
      int a = (k1 * n1) & 63;
      re += cv[n1] * c64[a];
      im -= cv[n1] * s64[a];
    }
    A1p[(k1 << 6) + col] = make_float2(re, im);
  }
}

// ---------------- K4b: expansion stage B (n2 -> all k2), scalar A1-row loads ----------------
__global__ __launch_bounds__(256) void k_expB(const float* __restrict__ A1,
                                              float* __restrict__ A2) {
  const int t = threadIdx.x;
  const int kh = blockIdx.x;     // 0..1
  const int bc2 = blockIdx.y;
  const int k2 = t & 63;
  const int wid = __builtin_amdgcn_readfirstlane(t >> 6);
  float ctw[8], stw[8];
#pragma unroll
  for (int n2 = 0; n2 < 8; ++n2) {
    float ang = TWOPI_64 * ((k2 * n2) & 63);
    ctw[n2] = cosf(ang); stw[n2] = sinf(ang);
  }
  const float* A1b = A1 + ((size_t)bc2 << 13);
  for (int it = 0; it < 8; ++it) {
    int k1 = kh * 32 + it * 4 + wid;
    const float* ar = A1b + (k1 << 7);   // [n2][n3][2], wave-uniform -> s_load
    float re[8] = {0, 0, 0, 0, 0, 0, 0, 0}, im[8] = {0, 0, 0, 0, 0, 0, 0, 0};
#pragma unroll
    for (int n2 = 0; n2 < 8; ++n2) {
      float tc = ctw[n2], ts = stw[n2];
#pragma unroll
      for (int n3 = 0; n3 < 8; ++n3) {
        float a = ar[(n2 * 8 + n3) * 2];
        float b = ar[(n2 * 8 + n3) * 2 + 1];
        re[n3] += a * tc + b * ts;
        im[n3] += b * tc - a * ts;
      }
    }
    float out16[16];
#pragma unroll
    for (int n3 = 0; n3 < 8; ++n3) { out16[n3 * 2] = re[n3]; out16[n3 * 2 + 1] = im[n3]; }
    float4* dst = (float4*)(A2 + ((((size_t)bc2 * 64 + k1) * 64 + k2) << 4));
    const float4* s4 = (const float4*)out16;
    dst[0] = s4[0]; dst[1] = s4[1]; dst[2] = s4[2]; dst[3] = s4[3];
  }
}

// ---------------- K4c: expansion stage C (n3 -> all k3, fused flip term) + scale ----------------
__global__ __launch_bounds__(256) void k_expC(const float* __restrict__ A2,
                                              const float* __restrict__ inv2,
                                              float* __restrict__ out) {
  const int t = threadIdx.x;
  const int k1 = blockIdx.x;
  const int bc2 = blockIdx.y;
  const int k3 = t & 63;
  const int wid = __builtin_amdgcn_readfirstlane(t >> 6);
  float C1r[8], C2r[8];
  {
    float cj[9], sj[9];
#pragma unroll
    for (int jj = 0; jj < 9; ++jj) {
      float ang = TWOPI_64 * ((k3 * jj) & 63);
      cj[jj] = cosf(ang); sj[jj] = sinf(ang);
    }
#pragma unroll
    for (int n3 = 0; n3 < 8; ++n3) {
      C1r[n3] = cj[n3] - sj[n3 + 1];
      C2r[n3] = sj[n3] - cj[n3 + 1];
    }
  }
  const float sc = inv2[bc2];
  const float* Ab = A2 + (((size_t)bc2 * 64 + k1) << 10);
  float* dst = out + ((size_t)bc2 << 18) + (k1 << 12);
  for (int it = 0; it < 16; ++it) {
    int k2 = wid * 16 + it;
    const float* ar = Ab + (k2 << 4);   // wave-uniform -> s_load
    float acc = 0.f;
#pragma unroll
    for (int n3 = 0; n3 < 8; ++n3)
      acc += ar[n3 * 2] * C1r[n3] + ar[n3 * 2 + 1] * C2r[n3];
    dst[(k2 << 6) + k3] = acc * sc;
  }
}

extern "C" void kernel_launch(void* const* d_in, const int* in_sizes, int n_in,
                              void* d_out, int out_size, void* d_ws, size_t ws_size,
                              hipStream_t stream) {
  const float* x = (const float*)d_in[0];
  const float* w = (const float*)d_in[1];
  float* out = (float*)d_out;
  float* ws = (float*)d_ws;
  float* P    = ws + 0;
  float* red1 = ws + 8388608;
  float* xh   = ws + 8388992;
  float* conv = ws + 8454528;
  float* inv2 = ws + 8520064;
  float* A1   = ws + 8520192;
  float* A2   = ws + 0;   // alias P (dead after k_fwd2)

  hipMemsetAsync(red1, 0, 384 * sizeof(float), stream);
  k_fwd1<<<dim3(33, 128), 256, 0, stream>>>(x, P, red1);
  k_fwd2<<<dim3(8, 128), 256, 0, stream>>>(P, red1, xh);
  k_mix<<<dim3(128), 256, 0, stream>>>(xh, w, conv);
  k_expA<<<dim3(128), 256, 0, stream>>>(conv, A1, inv2);
  k_expB<<<dim3(2, 128), 256, 0, stream>>>(A1, A2);
  k_expC<<<dim3(64, 128), 256, 0, stream>>>(A2, inv2, out);
}

// Round 2
// 280.840 us; speedup vs baseline: 1.1935x; 1.1935x over previous
//
#include <hip/hip_runtime.h>
#include <math.h>

// SpectralConv3d via DHT identities (same math as round 1, re-fused):
//   r = Re(F) - Im(G);  ||r||^2 = (N^3/2)(2*sum x^2 + c1 - c2)  [cross term = 0]
//   corner: n3->k3 (stage1), n2->k2 (stage2, now fused into k_fwd1), n1->k1 (k_fwd2s)
//   mix: conv = 0.5*sum_i[(x+xn)w + (x-xn)wn];  ||Y||^2 = (N^3/2)(2*sum conv^2 + conv000^2)
//   expand: n1->k1 (A1), n2->k2 (B2, LDS), n3->k3 with C1/C2 fused flip term.

constexpr int NT = 262144;  // 64^3
constexpr float TWOPI_64 = 0.09817477042468103f;  // 2*pi/64

// ws float offsets:
//   S     [128][64][2][64][2] : 2097152 at 0        (8.4 MB)
//   red1p [128][33][3]        : 12672   at 2097152
//   xh    [128][512]          : 65536   at 2109824
//   inv2  [128]               : 128     at 2175360
//   A1    [128][8192]         : 1048576 at 2175488  (total ~12.9 MB)

// ---------------- K1: stage1 (n3->k3) + stage2 (n2->k2) + norm partials ----------------
__global__ __launch_bounds__(256) void k_fwd1(const float* __restrict__ x,
                                              float* __restrict__ S,
                                              float* __restrict__ red1p) {
  __shared__ float As[64 * 68];   // pad 68: 16B-aligned rows for ds_read_b128
  __shared__ float Bs[64 * 68];
  __shared__ float PL[32 * 65];   // stage1 output: rr = row*16 + f*8 + k3
  __shared__ float c64v[64], s64v[64];
  __shared__ float rsm[12];
  const int t = threadIdx.x;
  const int j = blockIdx.x;       // 0..32
  const int bc = blockIdx.y;      // 0..127
  const int n1a = j, n1b = (64 - j) & 63;
  const bool paired = (n1a != n1b);
  if (t < 64) { float ang = TWOPI_64 * t; c64v[t] = cosf(ang); s64v[t] = sinf(ang); }
  const float4* xa4 = (const float4*)(x + ((size_t)bc << 18) + (n1a << 12));
  const float4* xb4 = (const float4*)(x + ((size_t)bc << 18) + (n1b << 12));
  float ssp = 0.f;
  for (int q = 0; q < 4; ++q) {
    int l4 = t + (q << 8);
    int fl = l4 << 2;
    int r = fl >> 6, c = fl & 63;
    float4 va = xa4[l4], vb = xb4[l4];
    *(float4*)&As[r * 68 + c] = va;
    *(float4*)&Bs[r * 68 + c] = vb;
    ssp += va.x * va.x + va.y * va.y + va.z * va.z + va.w * va.w;
    if (paired) ssp += vb.x * vb.x + vb.y * vb.y + vb.z * vb.z + vb.w * vb.w;
  }
  __syncthreads();
  const int n2 = t & 63;
  const int k3a = t >> 6, k3b = k3a + 4;
  {  // stage 1: contract n3 for k3a,k3b over rows A,B
    float ca = 1.f, sa = 0.f, cb = 1.f, sb = 0.f;
    const float dca = c64v[k3a], dsa = s64v[k3a];
    const float dcb = c64v[k3b], dsb = s64v[k3b];
    float reA0 = 0, imA0 = 0, reA1 = 0, imA1 = 0;
    float reB0 = 0, imB0 = 0, reB1 = 0, imB1 = 0;
    const float4* Ar = (const float4*)&As[n2 * 68];
    const float4* Br = (const float4*)&Bs[n2 * 68];
    for (int m = 0; m < 16; ++m) {
      float4 va = Ar[m], vb = Br[m];
      float av[4] = {va.x, va.y, va.z, va.w};
      float bv[4] = {vb.x, vb.y, vb.z, vb.w};
#pragma unroll
      for (int e = 0; e < 4; ++e) {
        float a = av[e], b = bv[e];
        reA0 += a * ca; imA0 -= a * sa;
        reB0 += b * ca; imB0 -= b * sa;
        reA1 += a * cb; imA1 -= a * sb;
        reB1 += b * cb; imB1 -= b * sb;
        float nca = ca * dca - sa * dsa; sa = sa * dca + ca * dsa; ca = nca;
        float ncb = cb * dcb - sb * dsb; sb = sb * dcb + cb * dsb; cb = ncb;
      }
    }
    PL[(k3a) * 65 + n2] = reA0;      PL[(8 + k3a) * 65 + n2] = imA0;
    PL[(16 + k3a) * 65 + n2] = reB0; PL[(24 + k3a) * 65 + n2] = imB0;
    PL[(k3b) * 65 + n2] = reA1;      PL[(8 + k3b) * 65 + n2] = imA1;
    PL[(16 + k3b) * 65 + n2] = reB1; PL[(24 + k3b) * 65 + n2] = imB1;
  }
  // norm partials c1,c2 (ss done at load)
  float c1p = 0.f, c2p = 0.f;
  for (int q = 0; q < 16; ++q) {
    int l = t + (q << 8);
    int r = l >> 6, c = l & 63;
    float a = As[r * 68 + c];
    int m2 = (64 - r) & 63;
    int m3 = (64 - c) & 63;
    int m3b = (62 - c) & 63;
    c1p += a * Bs[m2 * 68 + m3];
    c2p += a * Bs[m2 * 68 + m3b];
  }
  if (paired) { c1p *= 2.f; c2p *= 2.f; }
  for (int off = 32; off; off >>= 1) {
    ssp += __shfl_down(ssp, off);
    c1p += __shfl_down(c1p, off);
    c2p += __shfl_down(c2p, off);
  }
  const int lane = t & 63, wid = t >> 6;
  if (lane == 0) { rsm[wid * 3] = ssp; rsm[wid * 3 + 1] = c1p; rsm[wid * 3 + 2] = c2p; }
  __syncthreads();   // covers PL writes + rsm
  if (t == 0) {
    red1p[((size_t)bc * 33 + j) * 3 + 0] = rsm[0] + rsm[3] + rsm[6] + rsm[9];
    red1p[((size_t)bc * 33 + j) * 3 + 1] = rsm[1] + rsm[4] + rsm[7] + rsm[10];
    red1p[((size_t)bc * 33 + j) * 3 + 2] = rsm[2] + rsm[5] + rsm[8] + rsm[11];
  }
  {  // stage 2: contract n2 for 8 k2, one (row,f,k3,k2) per thread
    const int k2 = t & 7;
    const int rr = t >> 3;
    const int row = rr >> 4, f = (rr >> 3) & 1, k3 = rr & 7;
    float rc = 1.f, rs = 0.f;
    const float dc = c64v[k2], ds = s64v[k2];
    float re = 0.f, im = 0.f;
    const float* pr = &PL[rr * 65];
    for (int n2i = 0; n2i < 64; ++n2i) {
      float v = pr[n2i];
      re += v * rc; im -= v * rs;
      float nc = rc * dc - rs * ds; rs = rs * dc + rc * ds; rc = nc;
    }
    const int n1row = row ? n1b : n1a;
    ((float2*)S)[(((size_t)bc * 64 + n1row) * 2 + f) * 64 + k2 * 8 + k3] =
        make_float2(re, im);
  }
}

// ---------------- K2: stage3 (n1->k1) + corner r + normalize ----------------
__global__ __launch_bounds__(256) void k_fwd2s(const float* __restrict__ S,
                                               const float* __restrict__ red1p,
                                               float* __restrict__ xh) {
  __shared__ float2 U3L[1024];
  __shared__ float c64v[64], s64v[64];
  __shared__ float rbuf[99];
  const int t = threadIdx.x;
  const int bc = blockIdx.x;
  if (t < 64) { float ang = TWOPI_64 * t; c64v[t] = cosf(ang); s64v[t] = sinf(ang); }
  if (t < 99) rbuf[t] = red1p[(size_t)bc * 99 + t];
  __syncthreads();
  {
    const int rr2 = t & 127;          // f*64 + k2*8 + k3
    const int k1g = t >> 7;
    const float2* Sb = (const float2*)(S + ((size_t)bc << 14));
    float rc[4], rs[4], dc[4], ds[4], re[4], im[4];
#pragma unroll
    for (int m = 0; m < 4; ++m) {
      int k1 = k1g * 4 + m;
      rc[m] = 1.f; rs[m] = 0.f; dc[m] = c64v[k1]; ds[m] = s64v[k1];
      re[m] = 0.f; im[m] = 0.f;
    }
#pragma unroll 4
    for (int n1 = 0; n1 < 64; ++n1) {
      float2 ab = Sb[(n1 << 7) + rr2];   // coalesced 512B per wave
#pragma unroll
      for (int m = 0; m < 4; ++m) {
        re[m] += ab.x * rc[m] + ab.y * rs[m];
        im[m] += ab.y * rc[m] - ab.x * rs[m];
        float nc = rc[m] * dc[m] - rs[m] * ds[m];
        rs[m] = rs[m] * dc[m] + rc[m] * ds[m];
        rc[m] = nc;
      }
    }
    const int f = rr2 >> 6, k2 = (rr2 >> 3) & 7, k3 = rr2 & 7;
#pragma unroll
    for (int m = 0; m < 4; ++m) {
      int k1 = k1g * 4 + m;
      U3L[f * 512 + k1 * 64 + k2 * 8 + k3] = make_float2(re[m], im[m]);
    }
  }
  __syncthreads();
  float ss = 0.f, c1 = 0.f, c2 = 0.f;
  for (int jj = 0; jj < 33; ++jj) {
    ss += rbuf[jj * 3];
    c1 += rbuf[jj * 3 + 1];
    c2 += rbuf[jj * 3 + 2];
  }
  float nsq = 0.5f * (float)NT * (2.f * ss + c1 - c2);
  float inv1 = nsq > 0.f ? rsqrtf(nsq) : 0.f;
  for (int q = 0; q < 2; ++q) {
    int kk = t + (q << 8);
    int k1 = kk >> 6, k2 = (kk >> 3) & 7, k3 = kk & 7;
    float2 U = U3L[k1 * 64 + k2 * 8 + k3];
    float2 V = U3L[512 + k1 * 64 + k2 * 8 + k3];
    float ct = c64v[k3], st = s64v[k3];
    float r = U.x - V.y - st * (U.x + V.y) - ct * (U.y - V.x);
    xh[(size_t)bc * 512 + kk] = r * inv1;
  }
}

// ---------------- K3: channel mixing + expansion stage A + second norm (fused) ----------------
__global__ __launch_bounds__(256) void k_mixA(const float* __restrict__ xh,
                                              const float* __restrict__ w,
                                              float* __restrict__ A1,
                                              float* __restrict__ inv2) {
  __shared__ float xsh[16384];   // exactly 64 KB; conv + tables reuse dead regions
  const int t = threadIdx.x;
  const int bc2 = blockIdx.x;
  const int b = bc2 >> 5, o = bc2 & 31;
  const float4* xb4 = (const float4*)(xh + ((size_t)b << 14));
  float4* xs4 = (float4*)xsh;
  for (int q = 0; q < 16; ++q) xs4[t + (q << 8)] = xb4[t + (q << 8)];
  __syncthreads();
  float acc0 = 0.f, acc1 = 0.f;
  {
    int k0 = t, kq1 = t + 256;
    int k1 = k0 >> 6, k2 = (k0 >> 3) & 7, k3 = k0 & 7;
    int nk0 = (((8 - k1) & 7) << 6) + (((8 - k2) & 7) << 3) + ((8 - k3) & 7);
    int l1 = kq1 >> 6, l2 = (kq1 >> 3) & 7, l3 = kq1 & 7;
    int nk1 = (((8 - l1) & 7) << 6) + (((8 - l2) & 7) << 3) + ((8 - l3) & 7);
    for (int i = 0; i < 32; ++i) {
      const float* wr = w + (((size_t)i * 32 + o) << 9);
      float xa0 = xsh[(i << 9) + k0],  xn0 = xsh[(i << 9) + nk0];
      float xa1 = xsh[(i << 9) + kq1], xn1 = xsh[(i << 9) + nk1];
      acc0 += (xa0 + xn0) * wr[k0]  + (xa0 - xn0) * wr[nk0];
      acc1 += (xa1 + xn1) * wr[kq1] + (xa1 - xn1) * wr[nk1];
    }
  }
  __syncthreads();               // all xsh reads done
  xsh[t] = 0.5f * acc0;          // conv -> xsh[0..511] (channel-0 region, dead)
  xsh[t + 256] = 0.5f * acc1;
  if (t < 64) {                  // twiddle tables -> xsh[512..639] (dead region)
    float ang = TWOPI_64 * t;
    xsh[512 + t] = cosf(ang);
    xsh[576 + t] = sinf(ang);
  }
  __syncthreads();
  const int col = t & 63;
  const int quarter = t >> 6;
  float cv[8];
#pragma unroll
  for (int n1 = 0; n1 < 8; ++n1) cv[n1] = xsh[(n1 << 6) + col];
  if (quarter == 0) {
    float p = 0.f;
#pragma unroll
    for (int n1 = 0; n1 < 8; ++n1) p += cv[n1] * cv[n1];
    for (int off = 32; off; off >>= 1) p += __shfl_down(p, off);
    if (t == 0) {
      float c000 = cv[0];
      float nsq = 0.5f * (float)NT * (2.f * p + c000 * c000);
      float nrm = sqrtf(nsq);
      inv2[bc2] = nrm > 0.f ? 1.f / (nrm * (float)NT) : 0.f;
    }
  }
  float2* A1p = (float2*)(A1 + ((size_t)bc2 << 13));
  for (int it = 0; it < 16; ++it) {
    int k1 = quarter + (it << 2);
    float re = 0.f, im = 0.f;
#pragma unroll
    for (int n1 = 0; n1 < 8; ++n1) {
      int a = (k1 * n1) & 63;
      re += cv[n1] * xsh[512 + a];
      im -= cv[n1] * xsh[576 + a];
    }
    A1p[(k1 << 6) + col] = make_float2(re, im);
  }
}

// ---------------- K4: expansion stages B+C fused (A2 eliminated) ----------------
__global__ __launch_bounds__(256) void k_expBC(const float* __restrict__ A1,
                                               const float* __restrict__ inv2,
                                               float* __restrict__ out) {
  __shared__ float arow[128];
  __shared__ float B2[64 * 17];   // [k2][f*8+n3], pad 17 -> stage-B writes 2-way max
  __shared__ float c64v[64], s64v[64];
  const int t = threadIdx.x;
  const int k1 = blockIdx.x;
  const int bc2 = blockIdx.y;
  if (t < 64) { float ang = TWOPI_64 * t; c64v[t] = cosf(ang); s64v[t] = sinf(ang); }
  if (t < 128) arow[t] = A1[((size_t)bc2 << 13) + (k1 << 7) + t];
  __syncthreads();
  {  // stage B: contract n2 for all 64 k2; thread = (k2, f, n3-quad)
    const int k2 = t & 63;
    const int g = t >> 6;
    const int f = g & 1;
    const int n3h = (g >> 1) << 2;
    float acc[4] = {0, 0, 0, 0};
    for (int n2i = 0; n2i < 8; ++n2i) {
      int a_ = (k2 * n2i) & 63;
      float tc = c64v[a_], ts = s64v[a_];
#pragma unroll
      for (int e = 0; e < 4; ++e) {
        int n3 = n3h + e;
        float a = arow[((n2i << 3) + n3) << 1];        // broadcast (lane-uniform)
        float b = arow[(((n2i << 3) + n3) << 1) + 1];
        acc[e] += (f == 0) ? (a * tc + b * ts) : (b * tc - a * ts);
      }
    }
#pragma unroll
    for (int e = 0; e < 4; ++e) B2[k2 * 17 + (f << 3) + n3h + e] = acc[e];
  }
  __syncthreads();
  {  // stage C: contract n3 for all k3 with fused flip coefficients
    const int k3 = t & 63;
    const int wid = t >> 6;
    float C1r[8], C2r[8];
#pragma unroll
    for (int n3 = 0; n3 < 8; ++n3) {
      int a0 = (k3 * n3) & 63;
      int a1 = (k3 * (n3 + 1)) & 63;
      C1r[n3] = c64v[a0] - s64v[a1];
      C2r[n3] = s64v[a0] - c64v[a1];
    }
    const float sc = inv2[bc2];
    float* dst = out + ((size_t)bc2 << 18) + (k1 << 12);
    for (int it = 0; it < 16; ++it) {
      int k2 = (wid << 4) + it;
      const float* br = &B2[k2 * 17];                  // wave-uniform -> broadcast
      float acc = 0.f;
#pragma unroll
      for (int n3 = 0; n3 < 8; ++n3) acc += br[n3] * C1r[n3] + br[8 + n3] * C2r[n3];
      dst[(k2 << 6) + k3] = acc * sc;
    }
  }
}

extern "C" void kernel_launch(void* const* d_in, const int* in_sizes, int n_in,
                              void* d_out, int out_size, void* d_ws, size_t ws_size,
                              hipStream_t stream) {
  const float* x = (const float*)d_in[0];
  const float* w = (const float*)d_in[1];
  float* out = (float*)d_out;
  float* ws = (float*)d_ws;
  float* S     = ws;
  float* red1p = ws + 2097152;
  float* xh    = ws + 2109824;
  float* inv2  = ws + 2175360;
  float* A1    = ws + 2175488;

  k_fwd1 <<<dim3(33, 128), 256, 0, stream>>>(x, S, red1p);
  k_fwd2s<<<dim3(128),     256, 0, stream>>>(S, red1p, xh);
  k_mixA <<<dim3(128),     256, 0, stream>>>(xh, w, A1, inv2);
  k_expBC<<<dim3(64, 128), 256, 0, stream>>>(A1, inv2, out);
}

// Round 3
// 274.530 us; speedup vs baseline: 1.2209x; 1.0230x over previous
//
#include <hip/hip_runtime.h>
#include <math.h>

// SpectralConv3d via DHT identities:
//   r = Re(F) - Im(G);  ||r||^2 = (N^3/2)(2*sum x^2 + c1 - c2)  [cross term = 0]
//   corner: n3->k3 + n2->k2 fused (k_fwd1), n1->k1 (k_fwd2s)
//   mix: conv = 0.5*sum_i[(x+xn)w + (x-xn)wn];  ||Y||^2 = (N^3/2)(2*sum conv^2 + conv000^2)
//   expand: n1->k1 (A1), n2->k2 (B2, LDS), n3->k3 with C1/C2 fused flip term.

constexpr int NT = 262144;  // 64^3
constexpr float TWOPI_64 = 0.09817477042468103f;  // 2*pi/64

// ws float offsets:
//   S     [128][64][2][64][2] : 2097152 at 0        (8.4 MB)
//   red1p [128][33][3]        : 12672   at 2097152
//   xh    [128][512]          : 65536   at 2109824
//   inv2  [128]               : 128     at 2175360
//   A1    [128][8192]         : 1048576 at 2175488  (total ~12.9 MB)

// ---------------- K1: stage1 (n3->k3) + stage2 (n2->k2) + norm partials ----------------
__global__ __launch_bounds__(256) void k_fwd1(const float* __restrict__ x,
                                              float* __restrict__ S,
                                              float* __restrict__ red1p) {
  __shared__ float As[64 * 68];   // pad 68: 16B-aligned rows for ds_read_b128
  __shared__ float Bs[64 * 68];
  __shared__ float PL[32 * 65];   // stage1 output: rr = row*16 + f*8 + k3
  __shared__ float c64v[64], s64v[64];
  __shared__ float rsm[12];
  const int t = threadIdx.x;
  const int j = blockIdx.x;       // 0..32
  const int bc = blockIdx.y;      // 0..127
  const int n1a = j, n1b = (64 - j) & 63;
  const bool paired = (n1a != n1b);
  if (t < 64) { float ang = TWOPI_64 * t; c64v[t] = cosf(ang); s64v[t] = sinf(ang); }
  const float4* xa4 = (const float4*)(x + ((size_t)bc << 18) + (n1a << 12));
  const float4* xb4 = (const float4*)(x + ((size_t)bc << 18) + (n1b << 12));
  float ssp = 0.f;
  for (int q = 0; q < 4; ++q) {
    int l4 = t + (q << 8);
    int fl = l4 << 2;
    int r = fl >> 6, c = fl & 63;
    float4 va = xa4[l4], vb = xb4[l4];
    *(float4*)&As[r * 68 + c] = va;
    *(float4*)&Bs[r * 68 + c] = vb;
    ssp += va.x * va.x + va.y * va.y + va.z * va.z + va.w * va.w;
    if (paired) ssp += vb.x * vb.x + vb.y * vb.y + vb.z * vb.z + vb.w * vb.w;
  }
  __syncthreads();
  const int n2 = t & 63;
  const int k3a = t >> 6, k3b = k3a + 4;
  {  // stage 1: contract n3 for k3a,k3b over rows A,B
    float ca = 1.f, sa = 0.f, cb = 1.f, sb = 0.f;
    const float dca = c64v[k3a], dsa = s64v[k3a];
    const float dcb = c64v[k3b], dsb = s64v[k3b];
    float reA0 = 0, imA0 = 0, reA1 = 0, imA1 = 0;
    float reB0 = 0, imB0 = 0, reB1 = 0, imB1 = 0;
    const float4* Ar = (const float4*)&As[n2 * 68];
    const float4* Br = (const float4*)&Bs[n2 * 68];
    for (int m = 0; m < 16; ++m) {
      float4 va = Ar[m], vb = Br[m];
      float av[4] = {va.x, va.y, va.z, va.w};
      float bv[4] = {vb.x, vb.y, vb.z, vb.w};
#pragma unroll
      for (int e = 0; e < 4; ++e) {
        float a = av[e], b = bv[e];
        reA0 += a * ca; imA0 -= a * sa;
        reB0 += b * ca; imB0 -= b * sa;
        reA1 += a * cb; imA1 -= a * sb;
        reB1 += b * cb; imB1 -= b * sb;
        float nca = ca * dca - sa * dsa; sa = sa * dca + ca * dsa; ca = nca;
        float ncb = cb * dcb - sb * dsb; sb = sb * dcb + cb * dsb; cb = ncb;
      }
    }
    PL[(k3a) * 65 + n2] = reA0;      PL[(8 + k3a) * 65 + n2] = imA0;
    PL[(16 + k3a) * 65 + n2] = reB0; PL[(24 + k3a) * 65 + n2] = imB0;
    PL[(k3b) * 65 + n2] = reA1;      PL[(8 + k3b) * 65 + n2] = imA1;
    PL[(16 + k3b) * 65 + n2] = reB1; PL[(24 + k3b) * 65 + n2] = imB1;
  }
  // norm partials c1,c2 (ss done at load)
  float c1p = 0.f, c2p = 0.f;
  for (int q = 0; q < 16; ++q) {
    int l = t + (q << 8);
    int r = l >> 6, c = l & 63;
    float a = As[r * 68 + c];
    int m2 = (64 - r) & 63;
    int m3 = (64 - c) & 63;
    int m3b = (62 - c) & 63;
    c1p += a * Bs[m2 * 68 + m3];
    c2p += a * Bs[m2 * 68 + m3b];
  }
  if (paired) { c1p *= 2.f; c2p *= 2.f; }
  for (int off = 32; off; off >>= 1) {
    ssp += __shfl_down(ssp, off);
    c1p += __shfl_down(c1p, off);
    c2p += __shfl_down(c2p, off);
  }
  const int lane = t & 63, wid = t >> 6;
  if (lane == 0) { rsm[wid * 3] = ssp; rsm[wid * 3 + 1] = c1p; rsm[wid * 3 + 2] = c2p; }
  __syncthreads();   // covers PL writes + rsm
  if (t == 0) {
    red1p[((size_t)bc * 33 + j) * 3 + 0] = rsm[0] + rsm[3] + rsm[6] + rsm[9];
    red1p[((size_t)bc * 33 + j) * 3 + 1] = rsm[1] + rsm[4] + rsm[7] + rsm[10];
    red1p[((size_t)bc * 33 + j) * 3 + 2] = rsm[2] + rsm[5] + rsm[8] + rsm[11];
  }
  {  // stage 2: contract n2 for 8 k2, one (row,f,k3,k2) per thread
    const int k2 = t & 7;
    const int rr = t >> 3;
    const int row = rr >> 4, f = (rr >> 3) & 1, k3 = rr & 7;
    float rc = 1.f, rs = 0.f;
    const float dc = c64v[k2], ds = s64v[k2];
    float re = 0.f, im = 0.f;
    const float* pr = &PL[rr * 65];
    for (int n2i = 0; n2i < 64; ++n2i) {
      float v = pr[n2i];
      re += v * rc; im -= v * rs;
      float nc = rc * dc - rs * ds; rs = rs * dc + rc * ds; rc = nc;
    }
    const int n1row = row ? n1b : n1a;
    ((float2*)S)[(((size_t)bc * 64 + n1row) * 2 + f) * 64 + k2 * 8 + k3] =
        make_float2(re, im);
  }
}

// ---------------- K2: stage3 (n1->k1) + corner r + normalize ----------------
// grid (2,128): h splits the k2k3 range; both f halves stay in-block for the combine.
__global__ __launch_bounds__(256) void k_fwd2s(const float* __restrict__ S,
                                               const float* __restrict__ red1p,
                                               float* __restrict__ xh) {
  __shared__ float2 U3L[512];     // [f][k1][kk&31]
  __shared__ float c64v[64], s64v[64];
  __shared__ float rbuf[99];
  const int t = threadIdx.x;
  const int h = blockIdx.x;       // 0..1
  const int bc = blockIdx.y;
  if (t < 64) { float ang = TWOPI_64 * t; c64v[t] = cosf(ang); s64v[t] = sinf(ang); }
  if (t < 99) rbuf[t] = red1p[(size_t)bc * 99 + t];
  __syncthreads();
  {
    const int kkl = t & 31;
    const int f = (t >> 5) & 1;
    const int k1g = t >> 6;            // 0..3, 2 k1 each
    const int rr2 = f * 64 + h * 32 + kkl;
    const float2* Sb = (const float2*)(S + ((size_t)bc << 14));
    float rc[2], rs[2], dc[2], ds[2], re[2], im[2];
#pragma unroll
    for (int m = 0; m < 2; ++m) {
      int k1 = k1g * 2 + m;
      rc[m] = 1.f; rs[m] = 0.f; dc[m] = c64v[k1]; ds[m] = s64v[k1];
      re[m] = 0.f; im[m] = 0.f;
    }
#pragma unroll 4
    for (int n1 = 0; n1 < 64; ++n1) {
      float2 ab = Sb[(n1 << 7) + rr2];
#pragma unroll
      for (int m = 0; m < 2; ++m) {
        re[m] += ab.x * rc[m] + ab.y * rs[m];
        im[m] += ab.y * rc[m] - ab.x * rs[m];
        float nc = rc[m] * dc[m] - rs[m] * ds[m];
        rs[m] = rs[m] * dc[m] + rc[m] * ds[m];
        rc[m] = nc;
      }
    }
#pragma unroll
    for (int m = 0; m < 2; ++m) {
      int k1 = k1g * 2 + m;
      U3L[f * 256 + k1 * 32 + kkl] = make_float2(re[m], im[m]);
    }
  }
  __syncthreads();
  float ss = 0.f, c1 = 0.f, c2 = 0.f;
  for (int jj = 0; jj < 33; ++jj) {
    ss += rbuf[jj * 3];
    c1 += rbuf[jj * 3 + 1];
    c2 += rbuf[jj * 3 + 2];
  }
  float nsq = 0.5f * (float)NT * (2.f * ss + c1 - c2);
  float inv1 = nsq > 0.f ? rsqrtf(nsq) : 0.f;
  {
    const int k1 = t >> 5, kkl = t & 31;
    const int kk = h * 32 + kkl;
    const int k3 = kk & 7;
    float2 U = U3L[k1 * 32 + kkl];
    float2 V = U3L[256 + k1 * 32 + kkl];
    float ct = c64v[k3], st = s64v[k3];
    float r = U.x - V.y - st * (U.x + V.y) - ct * (U.y - V.x);
    xh[(size_t)bc * 512 + k1 * 64 + kk] = r * inv1;
  }
}

// ---------------- K3: channel mixing + expansion stage A + second norm (fused) ----------------
__global__ __launch_bounds__(256) void k_mixA(const float* __restrict__ xh,
                                              const float* __restrict__ w,
                                              float* __restrict__ A1,
                                              float* __restrict__ inv2) {
  __shared__ float xsh[16384];   // exactly 64 KB; conv + tables reuse dead regions
  const int t = threadIdx.x;
  const int bc2 = blockIdx.x;
  const int b = bc2 >> 5, o = bc2 & 31;
  const float4* xb4 = (const float4*)(xh + ((size_t)b << 14));
  float4* xs4 = (float4*)xsh;
  for (int q = 0; q < 16; ++q) xs4[t + (q << 8)] = xb4[t + (q << 8)];
  __syncthreads();
  float acc0 = 0.f, acc1 = 0.f;
  {
    int k0 = t, kq1 = t + 256;
    int k1 = k0 >> 6, k2 = (k0 >> 3) & 7, k3 = k0 & 7;
    int nk0 = (((8 - k1) & 7) << 6) + (((8 - k2) & 7) << 3) + ((8 - k3) & 7);
    int l1 = kq1 >> 6, l2 = (kq1 >> 3) & 7, l3 = kq1 & 7;
    int nk1 = (((8 - l1) & 7) << 6) + (((8 - l2) & 7) << 3) + ((8 - l3) & 7);
    for (int i = 0; i < 32; ++i) {
      const float* wr = w + (((size_t)i * 32 + o) << 9);
      float xa0 = xsh[(i << 9) + k0],  xn0 = xsh[(i << 9) + nk0];
      float xa1 = xsh[(i << 9) + kq1], xn1 = xsh[(i << 9) + nk1];
      acc0 += (xa0 + xn0) * wr[k0]  + (xa0 - xn0) * wr[nk0];
      acc1 += (xa1 + xn1) * wr[kq1] + (xa1 - xn1) * wr[nk1];
    }
  }
  __syncthreads();               // all xsh reads done
  xsh[t] = 0.5f * acc0;          // conv -> xsh[0..511] (channel-0 region, dead)
  xsh[t + 256] = 0.5f * acc1;
  if (t < 64) {                  // twiddle tables -> xsh[512..639] (dead region)
    float ang = TWOPI_64 * t;
    xsh[512 + t] = cosf(ang);
    xsh[576 + t] = sinf(ang);
  }
  __syncthreads();
  const int col = t & 63;
  const int quarter = t >> 6;
  float cv[8];
#pragma unroll
  for (int n1 = 0; n1 < 8; ++n1) cv[n1] = xsh[(n1 << 6) + col];
  if (quarter == 0) {
    float p = 0.f;
#pragma unroll
    for (int n1 = 0; n1 < 8; ++n1) p += cv[n1] * cv[n1];
    for (int off = 32; off; off >>= 1) p += __shfl_down(p, off);
    if (t == 0) {
      float c000 = cv[0];
      float nsq = 0.5f * (float)NT * (2.f * p + c000 * c000);
      float nrm = sqrtf(nsq);
      inv2[bc2] = nrm > 0.f ? 1.f / (nrm * (float)NT) : 0.f;
    }
  }
  float2* A1p = (float2*)(A1 + ((size_t)bc2 << 13));
  for (int it = 0; it < 16; ++it) {
    int k1 = quarter + (it << 2);
    float re = 0.f, im = 0.f;
#pragma unroll
    for (int n1 = 0; n1 < 8; ++n1) {
      int a = (k1 * n1) & 63;
      re += cv[n1] * xsh[512 + a];
      im -= cv[n1] * xsh[576 + a];
    }
    A1p[(k1 << 6) + col] = make_float2(re, im);
  }
}

// ---------------- K4: expansion stages B+C fused; vector LDS reads ----------------
__global__ __launch_bounds__(256) void k_expBC(const float* __restrict__ A1,
                                               const float* __restrict__ inv2,
                                               float* __restrict__ out) {
  __shared__ float arow[128];
  __shared__ float B2[64 * 20];   // [k2][f*8+n3] pad 20: rows 16B-aligned, groups disjoint
  __shared__ float c64v[64], s64v[64];
  const int t = threadIdx.x;
  const int k1 = blockIdx.x;
  const int bc2 = blockIdx.y;
  if (t < 64) { float ang = TWOPI_64 * t; c64v[t] = cosf(ang); s64v[t] = sinf(ang); }
  if (t < 128) arow[t] = A1[((size_t)bc2 << 13) + (k1 << 7) + t];
  __syncthreads();
  {  // stage B: contract n2 for all 64 k2; thread = (k2, f, n3-quad); g wave-uniform
    const int k2 = t & 63;
    const int g = t >> 6;
    const int f = g & 1;
    const int n3h = (g >> 1) << 2;
    float acc[4] = {0, 0, 0, 0};
    for (int n2i = 0; n2i < 8; ++n2i) {
      int a_ = (k2 * n2i) & 63;
      float tc = c64v[a_], ts = s64v[a_];
      const float4* ar4 = (const float4*)&arow[((n2i << 3) + n3h) << 1];
      float4 p0 = ar4[0];   // a0,b0,a1,b1  (uniform -> broadcast b128)
      float4 p1 = ar4[1];   // a2,b2,a3,b3
      if (f == 0) {
        acc[0] += p0.x * tc + p0.y * ts;
        acc[1] += p0.z * tc + p0.w * ts;
        acc[2] += p1.x * tc + p1.y * ts;
        acc[3] += p1.z * tc + p1.w * ts;
      } else {
        acc[0] += p0.y * tc - p0.x * ts;
        acc[1] += p0.w * tc - p0.z * ts;
        acc[2] += p1.y * tc - p1.x * ts;
        acc[3] += p1.w * tc - p1.z * ts;
      }
    }
    *(float4*)&B2[k2 * 20 + (f << 3) + n3h] = make_float4(acc[0], acc[1], acc[2], acc[3]);
  }
  __syncthreads();
  {  // stage C: contract n3 for all k3 with fused flip coefficients; b128 row reads
    const int k3 = t & 63;
    const int wid = t >> 6;
    float C1r[8], C2r[8];
#pragma unroll
    for (int n3 = 0; n3 < 8; ++n3) {
      int a0 = (k3 * n3) & 63;
      int a1 = (k3 * (n3 + 1)) & 63;
      C1r[n3] = c64v[a0] - s64v[a1];
      C2r[n3] = s64v[a0] - c64v[a1];
    }
    const float sc = inv2[bc2];
    float* dst = out + ((size_t)bc2 << 18) + (k1 << 12);
    for (int it = 0; it < 16; ++it) {
      int k2 = (wid << 4) + it;
      const float4* br4 = (const float4*)&B2[k2 * 20];   // uniform -> broadcast b128
      float4 r0 = br4[0], r1 = br4[1], r2 = br4[2], r3 = br4[3];
      float acc = r0.x * C1r[0] + r0.y * C1r[1] + r0.z * C1r[2] + r0.w * C1r[3]
                + r1.x * C1r[4] + r1.y * C1r[5] + r1.z * C1r[6] + r1.w * C1r[7]
                + r2.x * C2r[0] + r2.y * C2r[1] + r2.z * C2r[2] + r2.w * C2r[3]
                + r3.x * C2r[4] + r3.y * C2r[5] + r3.z * C2r[6] + r3.w * C2r[7];
      dst[(k2 << 6) + k3] = acc * sc;
    }
  }
}

extern "C" void kernel_launch(void* const* d_in, const int* in_sizes, int n_in,
                              void* d_out, int out_size, void* d_ws, size_t ws_size,
                              hipStream_t stream) {
  const float* x = (const float*)d_in[0];
  const float* w = (const float*)d_in[1];
  float* out = (float*)d_out;
  float* ws = (float*)d_ws;
  float* S     = ws;
  float* red1p = ws + 2097152;
  float* xh    = ws + 2109824;
  float* inv2  = ws + 2175360;
  float* A1    = ws + 2175488;

  k_fwd1 <<<dim3(33, 128), 256, 0, stream>>>(x, S, red1p);
  k_fwd2s<<<dim3(2, 128),  256, 0, stream>>>(S, red1p, xh);
  k_mixA <<<dim3(128),     256, 0, stream>>>(xh, w, A1, inv2);
  k_expBC<<<dim3(64, 128), 256, 0, stream>>>(A1, inv2, out);
}